// Round 3
// baseline (426.648 us; speedup 1.0000x reference)
//
#include <hip/hip_runtime.h>
#include <math.h>

#define BB 4
#define NN 4096
#define DIM 128
#define DE 512
#define NTOK (BB * NN)
#define CH 32               // tokens per chunk / per block
#define NCHUNK (NN / CH)    // 128 chunks per batch

typedef __attribute__((ext_vector_type(8))) short bf16x8;
typedef __attribute__((ext_vector_type(4))) float f32x4;
typedef unsigned short us;

// ---------- helpers ----------
__device__ inline us f2bf(float f) {
    union { float f; unsigned int u; } v; v.f = f;
    unsigned int r = v.u + 0x7FFF + ((v.u >> 16) & 1);   // RNE
    return (us)(r >> 16);
}
__device__ inline float bf2f(unsigned int h16) {
    union { unsigned int u; float f; } v; v.u = (h16 & 0xFFFFu) << 16;
    return v.f;
}
__device__ inline float gelu_erf(float x) {
    return 0.5f * x * (1.0f + erff(x * 0.70710678118654752f));
}
__device__ inline float sigmoidf(float x) {
    return 1.0f / (1.0f + expf(-x));
}

// =====================================================================
// K0: repack W_se[512x128], W_po[512x128], W_ag[128x512] fp32 -> bf16 in
// MFMA B-fragment-linear order: frag f = ct*n_ks+ks holds, at
// [f*512 + lane*8 + j], W[col=ct*16+(lane&15)][k=ks*32+(lane>>4)*8+j].
// A wave's B-frag load is then one contiguous 1 KB read.
// 3 matrices x 128 frags x 64 lanes = 24576 threads.
// =====================================================================
__global__ __launch_bounds__(256) void k0_pack(
    const float* __restrict__ Wse, const float* __restrict__ Wpo,
    const float* __restrict__ Wag, us* __restrict__ wp)
{
    int gid = blockIdx.x * 256 + threadIdx.x;
    int mat = gid >> 13;            // 8192 threads per matrix
    int r   = gid & 8191;
    int f   = r >> 6;               // frag id 0..127
    int lane = r & 63;
    const float* src = (mat == 0) ? Wse : ((mat == 1) ? Wpo : Wag);
    int K     = (mat == 2) ? DE : DIM;
    int shift = (mat == 2) ? 4 : 2;       // n_ks = K/32
    int ct = f >> shift;
    int ks = f & ((1 << shift) - 1);
    int col = ct * 16 + (lane & 15);
    int k0  = ks * 32 + (lane >> 4) * 8;
    const float* s = &src[(size_t)col * K + k0];
    float4 a = *(const float4*)s;
    float4 b = *(const float4*)(s + 4);
    us o[8] = { f2bf(a.x), f2bf(a.y), f2bf(a.z), f2bf(a.w),
                f2bf(b.x), f2bf(b.y), f2bf(b.z), f2bf(b.w) };
    us* d = wp + (size_t)mat * 65536 + ((size_t)f * 64 + lane) * 8;
    *(ushort4*)d       = *(ushort4*)&o[0];
    *(ushort4*)(d + 4) = *(ushort4*)&o[4];
}

// =====================================================================
// K1: per-chunk column sums of h = poly2(gelu(xq @ W_po^T + b_po)).
// No intermediate written to HBM -- only S [BB*NCHUNK][DE] fp32 (1 MB).
// Wave w: token half tg=w&1, col half chf=w>>1; lane owns col pair
// (c, c+256) so h2*h1 is register-local.
// =====================================================================
#define XPAD 8
__global__ __launch_bounds__(256) void k1_chunksums(
    const float* __restrict__ xq, const us* __restrict__ wpo,
    const float* __restrict__ b_po, float* __restrict__ S)
{
    __shared__ us xs[CH][DIM + XPAD];
    __shared__ float Ssum[DE];

    const int tid = threadIdx.x;
    const int blk = blockIdx.x;
    const size_t t0 = (size_t)blk * CH;

    Ssum[tid] = 0.f;
    Ssum[tid + 256] = 0.f;

    for (int i = tid * 4; i < CH * DIM; i += 1024) {
        int tok = i >> 7, k = i & 127;
        float4 v = *(const float4*)&xq[(t0 + tok) * DIM + k];
        ushort4 o = { f2bf(v.x), f2bf(v.y), f2bf(v.z), f2bf(v.w) };
        *(ushort4*)&xs[tok][k] = o;
    }
    __syncthreads();

    const int lane = tid & 63, w = tid >> 6;
    const int tg = w & 1, chf = w >> 1;
    const int l15 = lane & 15, q = lane >> 4;

    bf16x8 af[4];
    #pragma unroll
    for (int ks = 0; ks < 4; ++ks)
        af[ks] = *(const bf16x8*)&xs[tg * 16 + l15][ks * 32 + q * 8];

    f32x4 accL[8], accH[8];
    #pragma unroll
    for (int i = 0; i < 8; ++i) {
        accL[i] = (f32x4){0.f, 0.f, 0.f, 0.f};
        accH[i] = (f32x4){0.f, 0.f, 0.f, 0.f};
    }

    #pragma unroll
    for (int ks = 0; ks < 4; ++ks) {
        #pragma unroll
        for (int i = 0; i < 8; ++i) {
            int ctL = chf * 8 + i;
            bf16x8 bL = *(const bf16x8*)&wpo[(size_t)((ctL * 4 + ks) * 64 + lane) * 8];
            bf16x8 bH = *(const bf16x8*)&wpo[(size_t)(((ctL + 16) * 4 + ks) * 64 + lane) * 8];
            accL[i] = __builtin_amdgcn_mfma_f32_16x16x32_bf16(af[ks], bL, accL[i], 0, 0, 0);
            accH[i] = __builtin_amdgcn_mfma_f32_16x16x32_bf16(af[ks], bH, accH[i], 0, 0, 0);
        }
    }

    #pragma unroll
    for (int i = 0; i < 8; ++i) {
        int colL = (chf * 8 + i) * 16 + l15;
        int colH = colL + 256;
        float bL = b_po[colL], bH = b_po[colH];
        float sL = 0.f, sH = 0.f;
        #pragma unroll
        for (int r = 0; r < 4; ++r) {
            float g1 = gelu_erf(accL[i][r] + bL);
            float g2 = gelu_erf(accH[i][r] + bH);
            sL += g1;
            sH += g2 * g1;
        }
        sL += __shfl_xor(sL, 16); sL += __shfl_xor(sL, 32);
        sH += __shfl_xor(sH, 16); sH += __shfl_xor(sH, 32);
        if (q == 0) {
            atomicAdd(&Ssum[colL], sL);
            atomicAdd(&Ssum[colH], sH);
        }
    }
    __syncthreads();
    S[(size_t)blk * DE + tid]       = Ssum[tid];
    S[(size_t)blk * DE + tid + 256] = Ssum[tid + 256];
}

// =====================================================================
// K3: fully fused per-chunk:
//   - prefix of chunk sums (reads S rows [0..c) from L2)
//   - recompute h (MFMA + gelu/poly) -> LDS ht
//   - in-chunk running cumsum + causal mean -> agg (in-place over ht, bf16)
//   - recompute s (MFMA), gate o = sigmoid(s)*agg -> in-place over ht
//   - out-projection o @ W_ag^T + b_ag via MFMA
// LDS: 8.7 + 33.3 + 2 KB = 44 KB -> 3 blocks/CU.
// =====================================================================
#define OPAD 8
__global__ __launch_bounds__(256) void k3_fused(
    const float* __restrict__ xq, const us* __restrict__ wse,
    const us* __restrict__ wpo, const us* __restrict__ wag,
    const float* __restrict__ b_se, const float* __restrict__ b_po,
    const float* __restrict__ S, const float* __restrict__ b_ag,
    float* __restrict__ out)
{
    __shared__ us xs[CH][DIM + XPAD];
    __shared__ us ht[CH][DE + OPAD];   // h -> agg -> o (reused in place)
    __shared__ float pre[DE];

    const int tid = threadIdx.x;
    const int blk = blockIdx.x;
    const int c = blk & (NCHUNK - 1);
    const int b = blk >> 7;            // NCHUNK = 128
    const size_t t0 = (size_t)blk * CH;

    // stage x tile fp32 -> bf16
    for (int i = tid * 4; i < CH * DIM; i += 1024) {
        int tok = i >> 7, k = i & 127;
        float4 v = *(const float4*)&xq[(t0 + tok) * DIM + k];
        ushort4 o = { f2bf(v.x), f2bf(v.y), f2bf(v.z), f2bf(v.w) };
        *(ushort4*)&xs[tok][k] = o;
    }
    // exclusive prefix of chunk sums for this chunk
    {
        int d = tid * 2;
        float r0 = 0.f, r1 = 0.f;
        const float* p = &S[((size_t)b * NCHUNK) * DE + d];
        for (int cc = 0; cc < c; ++cc) {
            float2 v = *(const float2*)p;
            r0 += v.x; r1 += v.y;
            p += DE;
        }
        pre[d] = r0; pre[d + 1] = r1;
    }
    __syncthreads();

    const int lane = tid & 63, w = tid >> 6;
    const int tg = w & 1, chf = w >> 1;
    const int l15 = lane & 15, q = lane >> 4;

    bf16x8 af[4];
    #pragma unroll
    for (int ks = 0; ks < 4; ++ks)
        af[ks] = *(const bf16x8*)&xs[tg * 16 + l15][ks * 32 + q * 8];

    // ---- phase 1: h-GEMM -> gelu/poly -> ht ----
    {
        f32x4 accL[8], accH[8];
        #pragma unroll
        for (int i = 0; i < 8; ++i) {
            accL[i] = (f32x4){0.f, 0.f, 0.f, 0.f};
            accH[i] = (f32x4){0.f, 0.f, 0.f, 0.f};
        }
        #pragma unroll
        for (int ks = 0; ks < 4; ++ks) {
            #pragma unroll
            for (int i = 0; i < 8; ++i) {
                int ctL = chf * 8 + i;
                bf16x8 bL = *(const bf16x8*)&wpo[(size_t)((ctL * 4 + ks) * 64 + lane) * 8];
                bf16x8 bH = *(const bf16x8*)&wpo[(size_t)(((ctL + 16) * 4 + ks) * 64 + lane) * 8];
                accL[i] = __builtin_amdgcn_mfma_f32_16x16x32_bf16(af[ks], bL, accL[i], 0, 0, 0);
                accH[i] = __builtin_amdgcn_mfma_f32_16x16x32_bf16(af[ks], bH, accH[i], 0, 0, 0);
            }
        }
        #pragma unroll
        for (int i = 0; i < 8; ++i) {
            int colL = (chf * 8 + i) * 16 + l15;
            int colH = colL + 256;
            float bL = b_po[colL], bH = b_po[colH];
            #pragma unroll
            for (int r = 0; r < 4; ++r) {
                int tok = tg * 16 + q * 4 + r;
                float g1 = gelu_erf(accL[i][r] + bL);
                float g2 = gelu_erf(accH[i][r] + bH);
                ht[tok][colL] = f2bf(g1);
                ht[tok][colH] = f2bf(g2 * g1);
            }
        }
    }
    __syncthreads();

    // ---- phase 2: in-chunk cumsum + causal mean (in place, bf16) ----
    {
        int d = tid * 2;
        float r0 = pre[d], r1 = pre[d + 1];
        #pragma unroll 4
        for (int n = 0; n < CH; ++n) {
            unsigned hv = *(unsigned*)&ht[n][d];
            r0 += bf2f(hv);
            r1 += bf2f(hv >> 16);
            float inv = 1.0f / ((float)(c * CH + n + 1) + 1e-7f);
            *(unsigned*)&ht[n][d] = (unsigned)f2bf(r0 * inv)
                                  | ((unsigned)f2bf(r1 * inv) << 16);
        }
    }
    __syncthreads();

    // ---- phase 3: s-GEMM -> o = sigmoid(s) * agg (in place over ht) ----
    {
        f32x4 accL[8], accH[8];
        #pragma unroll
        for (int i = 0; i < 8; ++i) {
            accL[i] = (f32x4){0.f, 0.f, 0.f, 0.f};
            accH[i] = (f32x4){0.f, 0.f, 0.f, 0.f};
        }
        #pragma unroll
        for (int ks = 0; ks < 4; ++ks) {
            #pragma unroll
            for (int i = 0; i < 8; ++i) {
                int ctL = chf * 8 + i;
                bf16x8 bL = *(const bf16x8*)&wse[(size_t)((ctL * 4 + ks) * 64 + lane) * 8];
                bf16x8 bH = *(const bf16x8*)&wse[(size_t)(((ctL + 16) * 4 + ks) * 64 + lane) * 8];
                accL[i] = __builtin_amdgcn_mfma_f32_16x16x32_bf16(af[ks], bL, accL[i], 0, 0, 0);
                accH[i] = __builtin_amdgcn_mfma_f32_16x16x32_bf16(af[ks], bH, accH[i], 0, 0, 0);
            }
        }
        #pragma unroll
        for (int i = 0; i < 8; ++i) {
            int colL = (chf * 8 + i) * 16 + l15;
            int colH = colL + 256;
            float bL = b_se[colL], bH = b_se[colH];
            #pragma unroll
            for (int r = 0; r < 4; ++r) {
                int tok = tg * 16 + q * 4 + r;
                float aggL = bf2f((unsigned)ht[tok][colL]);
                float aggH = bf2f((unsigned)ht[tok][colH]);
                ht[tok][colL] = f2bf(sigmoidf(accL[i][r] + bL) * aggL);
                ht[tok][colH] = f2bf(sigmoidf(accH[i][r] + bH) * aggH);
            }
        }
    }
    __syncthreads();

    // ---- phase 4: out-projection o @ W_ag^T + b_ag ----
    {
        f32x4 acc[4];
        #pragma unroll
        for (int i = 0; i < 4; ++i) acc[i] = (f32x4){0.f, 0.f, 0.f, 0.f};

        for (int ks = 0; ks < 16; ++ks) {
            bf16x8 a = *(const bf16x8*)&ht[tg * 16 + l15][ks * 32 + q * 8];
            #pragma unroll
            for (int i = 0; i < 4; ++i) {
                int ct = chf * 4 + i;
                bf16x8 bb = *(const bf16x8*)&wag[(size_t)((ct * 16 + ks) * 64 + lane) * 8];
                acc[i] = __builtin_amdgcn_mfma_f32_16x16x32_bf16(a, bb, acc[i], 0, 0, 0);
            }
        }
        #pragma unroll
        for (int i = 0; i < 4; ++i) {
            int col = (chf * 4 + i) * 16 + l15;
            float bv = b_ag[col];
            #pragma unroll
            for (int r = 0; r < 4; ++r) {
                size_t tok = t0 + tg * 16 + q * 4 + r;
                out[tok * DIM + col] = acc[i][r] + bv;
            }
        }
    }
}

extern "C" void kernel_launch(void* const* d_in, const int* in_sizes, int n_in,
                              void* d_out, int out_size, void* d_ws, size_t ws_size,
                              hipStream_t stream)
{
    const float* xq   = (const float*)d_in[0];
    // d_in[1] = mask: causal tril -> replaced by prefix-sum algorithm
    const float* W_se = (const float*)d_in[2];
    const float* b_se = (const float*)d_in[3];
    const float* W_po = (const float*)d_in[4];
    const float* b_po = (const float*)d_in[5];
    const float* W_ag = (const float*)d_in[6];
    const float* b_ag = (const float*)d_in[7];
    float* out = (float*)d_out;

    us* wp  = (us*)d_ws;               // 3 x 65536 bf16, fragment-packed
    us* wse = wp;
    us* wpo = wp + 65536;
    us* wag = wp + 131072;
    float* S = (float*)(wp + 196608);  // [BB*NCHUNK][DE] fp32 chunk sums (1 MB)

    k0_pack<<<96, 256, 0, stream>>>(W_se, W_po, W_ag, wp);
    k1_chunksums<<<NTOK / CH, 256, 0, stream>>>(xq, wpo, b_po, S);
    k3_fused<<<NTOK / CH, 256, 0, stream>>>(xq, wse, wpo, wag,
                                            b_se, b_po, S, b_ag, out);
}

// Round 4
// 385.862 us; speedup vs baseline: 1.1057x; 1.1057x over previous
//
#include <hip/hip_runtime.h>
#include <math.h>

#define BB 4
#define NN 4096
#define DIM 128
#define DE 512
#define NTOK (BB * NN)
#define CH 32               // tokens per chunk / per block
#define NCHUNK (NN / CH)    // 128 chunks per batch

typedef __attribute__((ext_vector_type(8))) short bf16x8;
typedef __attribute__((ext_vector_type(4))) float f32x4;
typedef unsigned short us;

// ---------- helpers ----------
__device__ inline us f2bf(float f) {
    union { float f; unsigned int u; } v; v.f = f;
    unsigned int r = v.u + 0x7FFF + ((v.u >> 16) & 1);   // RNE
    return (us)(r >> 16);
}
__device__ inline float bf2f(unsigned int h16) {
    union { unsigned int u; float f; } v; v.u = (h16 & 0xFFFFu) << 16;
    return v.f;
}
__device__ inline float gelu_erf(float x) {
    return 0.5f * x * (1.0f + erff(x * 0.70710678118654752f));
}
__device__ inline float sigmoidf(float x) {
    return 1.0f / (1.0f + expf(-x));
}

// =====================================================================
// K0: repack W_se[512x128], W_po[512x128], W_ag[128x512] fp32 -> bf16 in
// MFMA B-fragment-linear order: frag f = ct*n_ks+ks holds, at
// [f*512 + lane*8 + j], W[col=ct*16+(lane&15)][k=ks*32+(lane>>4)*8+j].
// =====================================================================
__global__ __launch_bounds__(256) void k0_pack(
    const float* __restrict__ Wse, const float* __restrict__ Wpo,
    const float* __restrict__ Wag, us* __restrict__ wp)
{
    int gid = blockIdx.x * 256 + threadIdx.x;
    int mat = gid >> 13;            // 8192 threads per matrix
    int r   = gid & 8191;
    int f   = r >> 6;               // frag id 0..127
    int lane = r & 63;
    const float* src = (mat == 0) ? Wse : ((mat == 1) ? Wpo : Wag);
    int K     = (mat == 2) ? DE : DIM;
    int shift = (mat == 2) ? 4 : 2;       // n_ks = K/32
    int ct = f >> shift;
    int ks = f & ((1 << shift) - 1);
    int col = ct * 16 + (lane & 15);
    int k0  = ks * 32 + (lane >> 4) * 8;
    const float* s = &src[(size_t)col * K + k0];
    float4 a = *(const float4*)s;
    float4 b = *(const float4*)(s + 4);
    us o[8] = { f2bf(a.x), f2bf(a.y), f2bf(a.z), f2bf(a.w),
                f2bf(b.x), f2bf(b.y), f2bf(b.z), f2bf(b.w) };
    us* d = wp + (size_t)mat * 65536 + ((size_t)f * 64 + lane) * 8;
    *(ushort4*)d       = *(ushort4*)&o[0];
    *(ushort4*)(d + 4) = *(ushort4*)&o[4];
}

// =====================================================================
// K1: h-GEMM (xq @ W_po^T + b_po -> gelu -> poly2) via bf16 MFMA.
//   - writes hp in FRAGMENT-LINEAR layout (coalesced 16B/lane stores):
//     hp[(((blk*4+w)*8+i)*64+lane)*8 + j]:
//       j<4 : g1  at (tok=tg*16+q*4+j,     col=(chf*8+i)*16+l15)
//       j>=4: h2h1 at (tok=tg*16+q*4+j-4, col+256)
//   - fused per-chunk column sums -> S [BB*NCHUNK][DE] fp32
// LDS: xs 8.7 KB + Ssum 2 KB -> high occupancy.
// =====================================================================
#define XPAD 8
__global__ __launch_bounds__(256) void k1_hsum(
    const float* __restrict__ xq, const us* __restrict__ wpo,
    const float* __restrict__ b_po, us* __restrict__ hp,
    float* __restrict__ S)
{
    __shared__ us xs[CH][DIM + XPAD];
    __shared__ float Ssum[DE];

    const int tid = threadIdx.x;
    const int blk = blockIdx.x;
    const size_t t0 = (size_t)blk * CH;

    Ssum[tid] = 0.f;
    Ssum[tid + 256] = 0.f;

    for (int i = tid * 4; i < CH * DIM; i += 1024) {
        int tok = i >> 7, k = i & 127;
        float4 v = *(const float4*)&xq[(t0 + tok) * DIM + k];
        ushort4 o = { f2bf(v.x), f2bf(v.y), f2bf(v.z), f2bf(v.w) };
        *(ushort4*)&xs[tok][k] = o;
    }
    __syncthreads();

    const int lane = tid & 63, w = tid >> 6;
    const int tg = w & 1, chf = w >> 1;
    const int l15 = lane & 15, q = lane >> 4;

    bf16x8 af[4];
    #pragma unroll
    for (int ks = 0; ks < 4; ++ks)
        af[ks] = *(const bf16x8*)&xs[tg * 16 + l15][ks * 32 + q * 8];

    f32x4 accL[8], accH[8];
    #pragma unroll
    for (int i = 0; i < 8; ++i) {
        accL[i] = (f32x4){0.f, 0.f, 0.f, 0.f};
        accH[i] = (f32x4){0.f, 0.f, 0.f, 0.f};
    }

    #pragma unroll
    for (int ks = 0; ks < 4; ++ks) {
        #pragma unroll
        for (int i = 0; i < 8; ++i) {
            int ctL = chf * 8 + i;
            bf16x8 bL = *(const bf16x8*)&wpo[(size_t)((ctL * 4 + ks) * 64 + lane) * 8];
            bf16x8 bH = *(const bf16x8*)&wpo[(size_t)(((ctL + 16) * 4 + ks) * 64 + lane) * 8];
            accL[i] = __builtin_amdgcn_mfma_f32_16x16x32_bf16(af[ks], bL, accL[i], 0, 0, 0);
            accH[i] = __builtin_amdgcn_mfma_f32_16x16x32_bf16(af[ks], bH, accH[i], 0, 0, 0);
        }
    }

    #pragma unroll
    for (int i = 0; i < 8; ++i) {
        int colL = (chf * 8 + i) * 16 + l15;
        int colH = colL + 256;
        float bL = b_po[colL], bH = b_po[colH];
        float g1v[4], h2v[4];
        float sL = 0.f, sH = 0.f;
        #pragma unroll
        for (int r = 0; r < 4; ++r) {
            float g1 = gelu_erf(accL[i][r] + bL);
            float g2 = gelu_erf(accH[i][r] + bH);
            g1v[r] = g1;
            h2v[r] = g2 * g1;
            sL += g1;
            sH += h2v[r];
        }
        // coalesced 16B/lane fragment-linear store
        uint4 st;
        st.x = (unsigned)f2bf(g1v[0]) | ((unsigned)f2bf(g1v[1]) << 16);
        st.y = (unsigned)f2bf(g1v[2]) | ((unsigned)f2bf(g1v[3]) << 16);
        st.z = (unsigned)f2bf(h2v[0]) | ((unsigned)f2bf(h2v[1]) << 16);
        st.w = (unsigned)f2bf(h2v[2]) | ((unsigned)f2bf(h2v[3]) << 16);
        *(uint4*)&hp[((((size_t)blk * 4 + w) * 8 + i) * 64 + lane) * 8] = st;

        sL += __shfl_xor(sL, 16); sL += __shfl_xor(sL, 32);
        sH += __shfl_xor(sH, 16); sH += __shfl_xor(sH, 32);
        if (q == 0) {
            atomicAdd(&Ssum[colL], sL);
            atomicAdd(&Ssum[colH], sH);
        }
    }
    __syncthreads();
    S[(size_t)blk * DE + tid]       = Ssum[tid];
    S[(size_t)blk * DE + tid + 256] = Ssum[tid + 256];
}

// =====================================================================
// K3: per-chunk fused:
//   - prefix of chunk sums (S rows [0..c), L2-resident)
//   - load hp (fragment-linear, coalesced) -> scatter into ht LDS
//   - in-chunk running cumsum + causal mean (in place, bf16)
//   - s-GEMM (recompute from xq, L2-hot packed wse) -> sigmoid gate
//   - out-projection o @ W_ag^T + b_ag via MFMA
// LDS: 8.7 + 33.3 + 2 = 44 KB.
// =====================================================================
#define OPAD 8
__global__ __launch_bounds__(256) void k3_fused(
    const float* __restrict__ xq, const us* __restrict__ hp,
    const us* __restrict__ wse, const us* __restrict__ wag,
    const float* __restrict__ b_se, const float* __restrict__ S,
    const float* __restrict__ b_ag, float* __restrict__ out)
{
    __shared__ us xs[CH][DIM + XPAD];
    __shared__ us ht[CH][DE + OPAD];   // h -> agg -> o (in place)
    __shared__ float pre[DE];

    const int tid = threadIdx.x;
    const int blk = blockIdx.x;
    const int c = blk & (NCHUNK - 1);
    const int b = blk >> 7;
    const size_t t0 = (size_t)blk * CH;

    const int lane = tid & 63, w = tid >> 6;
    const int tg = w & 1, chf = w >> 1;
    const int l15 = lane & 15, q = lane >> 4;

    // issue hp fragment loads early (coalesced 16B/lane)
    uint4 hv[8];
    #pragma unroll
    for (int i = 0; i < 8; ++i)
        hv[i] = *(const uint4*)&hp[((((size_t)blk * 4 + w) * 8 + i) * 64 + lane) * 8];

    // stage x tile fp32 -> bf16
    for (int i = tid * 4; i < CH * DIM; i += 1024) {
        int tok = i >> 7, k = i & 127;
        float4 v = *(const float4*)&xq[(t0 + tok) * DIM + k];
        ushort4 o = { f2bf(v.x), f2bf(v.y), f2bf(v.z), f2bf(v.w) };
        *(ushort4*)&xs[tok][k] = o;
    }

    // exclusive prefix of chunk sums
    {
        int d = tid * 2;
        float r0 = 0.f, r1 = 0.f;
        const float* p = &S[((size_t)b * NCHUNK) * DE + d];
        for (int cc = 0; cc < c; ++cc) {
            float2 v = *(const float2*)p;
            r0 += v.x; r1 += v.y;
            p += DE;
        }
        pre[d] = r0; pre[d + 1] = r1;
    }

    // scatter hp fragments into ht[tok][col]
    #pragma unroll
    for (int i = 0; i < 8; ++i) {
        int colL = (chf * 8 + i) * 16 + l15;
        int colH = colL + 256;
        int tokb = tg * 16 + q * 4;
        ht[tokb + 0][colL] = (us)(hv[i].x);
        ht[tokb + 1][colL] = (us)(hv[i].x >> 16);
        ht[tokb + 2][colL] = (us)(hv[i].y);
        ht[tokb + 3][colL] = (us)(hv[i].y >> 16);
        ht[tokb + 0][colH] = (us)(hv[i].z);
        ht[tokb + 1][colH] = (us)(hv[i].z >> 16);
        ht[tokb + 2][colH] = (us)(hv[i].w);
        ht[tokb + 3][colH] = (us)(hv[i].w >> 16);
    }
    __syncthreads();

    // in-chunk cumsum + causal mean (in place, bf16)
    {
        int d = tid * 2;
        float r0 = pre[d], r1 = pre[d + 1];
        #pragma unroll 4
        for (int n = 0; n < CH; ++n) {
            unsigned hvv = *(unsigned*)&ht[n][d];
            r0 += bf2f(hvv);
            r1 += bf2f(hvv >> 16);
            float inv = 1.0f / ((float)(c * CH + n + 1) + 1e-7f);
            *(unsigned*)&ht[n][d] = (unsigned)f2bf(r0 * inv)
                                  | ((unsigned)f2bf(r1 * inv) << 16);
        }
    }
    __syncthreads();

    bf16x8 af[4];
    #pragma unroll
    for (int ks = 0; ks < 4; ++ks)
        af[ks] = *(const bf16x8*)&xs[tg * 16 + l15][ks * 32 + q * 8];

    // s-GEMM -> o = sigmoid(s) * agg (in place over ht)
    {
        f32x4 accL[8], accH[8];
        #pragma unroll
        for (int i = 0; i < 8; ++i) {
            accL[i] = (f32x4){0.f, 0.f, 0.f, 0.f};
            accH[i] = (f32x4){0.f, 0.f, 0.f, 0.f};
        }
        #pragma unroll
        for (int ks = 0; ks < 4; ++ks) {
            #pragma unroll
            for (int i = 0; i < 8; ++i) {
                int ctL = chf * 8 + i;
                bf16x8 bL = *(const bf16x8*)&wse[(size_t)((ctL * 4 + ks) * 64 + lane) * 8];
                bf16x8 bH = *(const bf16x8*)&wse[(size_t)(((ctL + 16) * 4 + ks) * 64 + lane) * 8];
                accL[i] = __builtin_amdgcn_mfma_f32_16x16x32_bf16(af[ks], bL, accL[i], 0, 0, 0);
                accH[i] = __builtin_amdgcn_mfma_f32_16x16x32_bf16(af[ks], bH, accH[i], 0, 0, 0);
            }
        }
        #pragma unroll
        for (int i = 0; i < 8; ++i) {
            int colL = (chf * 8 + i) * 16 + l15;
            int colH = colL + 256;
            float bL = b_se[colL], bH = b_se[colH];
            #pragma unroll
            for (int r = 0; r < 4; ++r) {
                int tok = tg * 16 + q * 4 + r;
                float aggL = bf2f((unsigned)ht[tok][colL]);
                float aggH = bf2f((unsigned)ht[tok][colH]);
                ht[tok][colL] = f2bf(sigmoidf(accL[i][r] + bL) * aggL);
                ht[tok][colH] = f2bf(sigmoidf(accH[i][r] + bH) * aggH);
            }
        }
    }
    __syncthreads();

    // out-projection o @ W_ag^T + b_ag
    {
        f32x4 acc[4];
        #pragma unroll
        for (int i = 0; i < 4; ++i) acc[i] = (f32x4){0.f, 0.f, 0.f, 0.f};

        for (int ks = 0; ks < 16; ++ks) {
            bf16x8 a = *(const bf16x8*)&ht[tg * 16 + l15][ks * 32 + q * 8];
            #pragma unroll
            for (int i = 0; i < 4; ++i) {
                int ct = chf * 4 + i;
                bf16x8 bb = *(const bf16x8*)&wag[(size_t)((ct * 16 + ks) * 64 + lane) * 8];
                acc[i] = __builtin_amdgcn_mfma_f32_16x16x32_bf16(a, bb, acc[i], 0, 0, 0);
            }
        }
        #pragma unroll
        for (int i = 0; i < 4; ++i) {
            int col = (chf * 4 + i) * 16 + l15;
            float bv = b_ag[col];
            #pragma unroll
            for (int r = 0; r < 4; ++r) {
                size_t tok = t0 + tg * 16 + q * 4 + r;
                out[tok * DIM + col] = acc[i][r] + bv;
            }
        }
    }
}

extern "C" void kernel_launch(void* const* d_in, const int* in_sizes, int n_in,
                              void* d_out, int out_size, void* d_ws, size_t ws_size,
                              hipStream_t stream)
{
    const float* xq   = (const float*)d_in[0];
    // d_in[1] = mask: causal tril -> replaced by prefix-sum algorithm
    const float* W_se = (const float*)d_in[2];
    const float* b_se = (const float*)d_in[3];
    const float* W_po = (const float*)d_in[4];
    const float* b_po = (const float*)d_in[5];
    const float* W_ag = (const float*)d_in[6];
    const float* b_ag = (const float*)d_in[7];
    float* out = (float*)d_out;

    us* wp  = (us*)d_ws;               // 3 x 65536 bf16, fragment-packed
    us* wse = wp;
    us* wpo = wp + 65536;
    us* wag = wp + 131072;
    float* S = (float*)(wp + 196608);  // [BB*NCHUNK][DE] fp32 chunk sums (1 MB)
    us* hp   = (us*)(S + (size_t)BB * NCHUNK * DE);   // [NTOK*DE] bf16, frag-linear

    k0_pack<<<96, 256, 0, stream>>>(W_se, W_po, W_ag, wp);
    k1_hsum<<<NTOK / CH, 256, 0, stream>>>(xq, wpo, b_po, hp, S);
    k3_fused<<<NTOK / CH, 256, 0, stream>>>(xq, hp, wse, wag, b_se, S, b_ag, out);
}